// Round 1
// baseline (4296.154 us; speedup 1.0000x reference)
//
#include <hip/hip_runtime.h>

#define DEVINL __device__ __forceinline__

constexpr int M_ = 2;      // channels / sources
constexpr int J_ = 3000;   // frames
constexpr int I_ = 2049;   // freq bins
constexpr int K_ = 8;      // NMF bases
constexpr int NITER = 30;
constexpr float EPS = 1e-20f;  // NMF_EPS == IP_EPS

constexpr int NSEG = 16;
constexpr int ISEG = (I_ + NSEG - 1) / NSEG;  // 129
constexpr int TJ = 256;
constexpr int NJT = (J_ + TJ - 1) / TJ;       // 12

DEVINL float waveRed(float v) {
#pragma unroll
  for (int off = 32; off > 0; off >>= 1) v += __shfl_xor(v, off, 64);
  return v;
}

// ---------------- init: copy T,V into ws; W = identity ----------------
__global__ void k_init(const float* __restrict__ Tin, const float* __restrict__ Vin,
                       float* __restrict__ T, float2* __restrict__ V2, float2* __restrict__ W2) {
  int idx = blockIdx.x * 256 + threadIdx.x;
  if (idx < I_ * K_ * 2) T[idx] = Tin[idx];
  if (idx < K_ * J_) V2[idx] = ((const float2*)Vin)[idx];
  if (idx < I_) {
    W2[idx * 4 + 0] = make_float2(1.f, 0.f);
    W2[idx * 4 + 1] = make_float2(0.f, 0.f);
    W2[idx * 4 + 2] = make_float2(0.f, 0.f);
    W2[idx * 4 + 3] = make_float2(1.f, 0.f);
  }
}

// ------------- transpose X (M,J,I) cplx -> Xt (M,I,J) cplx -------------
__global__ __launch_bounds__(256) void k_transpose(const float2* __restrict__ X, float2* __restrict__ Xt) {
  __shared__ float2 tile[32][33];
  int m = blockIdx.z;
  int i0 = blockIdx.x * 32, j0 = blockIdx.y * 32;
  int tx = threadIdx.x & 31, ty = threadIdx.x >> 5;
  for (int r = ty; r < 32; r += 8) {
    int j = j0 + r, i = i0 + tx;
    if (i < I_ && j < J_) tile[r][tx] = X[((size_t)m * J_ + j) * I_ + i];
  }
  __syncthreads();
  for (int r = ty; r < 32; r += 8) {
    int i = i0 + r, j = j0 + tx;
    if (i < I_ && j < J_) Xt[((size_t)m * I_ + i) * J_ + j] = tile[tx][r];
  }
}

// ---------------- pass A: Y|WX|^2, R, YdR store, T update ----------------
__global__ __launch_bounds__(256) void k_passA(const float2* __restrict__ Xt,
                                               const float2* __restrict__ W2,
                                               float* T, const float2* __restrict__ V2,
                                               float* __restrict__ YdR) {
  int i = blockIdx.x, t = threadIdx.x;
  float2 w00 = W2[i * 4 + 0], w01 = W2[i * 4 + 1], w10 = W2[i * 4 + 2], w11 = W2[i * 4 + 3];
  float T0[K_], T1[K_];
#pragma unroll
  for (int k = 0; k < K_; k++) {
    T0[k] = T[i * 2 * K_ + k * 2 + 0];
    T1[k] = T[i * 2 * K_ + k * 2 + 1];
  }
  float nT0[K_] = {}, dT0[K_] = {}, nT1[K_] = {}, dT1[K_] = {};
  const float2* x0r = Xt + (size_t)i * J_;
  const float2* x1r = Xt + ((size_t)I_ + i) * J_;
  float* y0r = YdR + (size_t)i * J_;
  float* y1r = YdR + ((size_t)I_ + i) * J_;
  for (int j = t; j < J_; j += 256) {
    float2 x0 = x0r[j], x1 = x1r[j];
    float y0re = w00.x * x0.x - w00.y * x0.y + w01.x * x1.x - w01.y * x1.y;
    float y0im = w00.x * x0.y + w00.y * x0.x + w01.x * x1.y + w01.y * x1.x;
    float y1re = w10.x * x0.x - w10.y * x0.y + w11.x * x1.x - w11.y * x1.y;
    float y1im = w10.x * x0.y + w10.y * x0.x + w11.x * x1.y + w11.y * x1.x;
    float a0 = y0re * y0re + y0im * y0im;
    float a1 = y1re * y1re + y1im * y1im;
    float2 v[K_];
    float R0 = 0.f, R1 = 0.f;
#pragma unroll
    for (int k = 0; k < K_; k++) {
      v[k] = V2[(size_t)k * J_ + j];
      R0 += T0[k] * v[k].x;
      R1 += T1[k] * v[k].y;
    }
    float ydr0 = a0 / (R0 * R0 + EPS), rd0 = 1.f / (R0 + EPS);
    float ydr1 = a1 / (R1 * R1 + EPS), rd1 = 1.f / (R1 + EPS);
    y0r[j] = ydr0;
    y1r[j] = ydr1;
#pragma unroll
    for (int k = 0; k < K_; k++) {
      nT0[k] += ydr0 * v[k].x;
      dT0[k] += rd0 * v[k].x;
      nT1[k] += ydr1 * v[k].y;
      dT1[k] += rd1 * v[k].y;
    }
  }
  // block-reduce 32 values
  __shared__ float red[4][32];
  __shared__ float out[32];
  int wave = t >> 6, lane = t & 63;
#pragma unroll
  for (int k = 0; k < K_; k++) {
    float a = waveRed(nT0[k]); if (lane == 0) red[wave][k] = a;
    float b = waveRed(dT0[k]); if (lane == 0) red[wave][8 + k] = b;
    float c = waveRed(nT1[k]); if (lane == 0) red[wave][16 + k] = c;
    float d = waveRed(dT1[k]); if (lane == 0) red[wave][24 + k] = d;
  }
  __syncthreads();
  if (t < 32) out[t] = red[0][t] + red[1][t] + red[2][t] + red[3][t];
  __syncthreads();
  if (t < 16) {
    int n = t >> 3, k = t & 7;
    float num = out[n * 16 + k];
    float den = out[n * 16 + 8 + k];
    float told = T[i * 2 * K_ + k * 2 + n];
    T[i * 2 * K_ + k * 2 + n] = told * sqrtf(num / (den + EPS));
  }
}

// -------- pass B: partial I-reductions for the V update (deterministic) --------
__global__ __launch_bounds__(256) void k_passB(const float* __restrict__ T,
                                               const float2* __restrict__ V2,
                                               const float* __restrict__ YdR,
                                               float* __restrict__ partial) {
  int t = threadIdx.x;
  int jt = blockIdx.x, s = blockIdx.y, n = blockIdx.z;
  int j = jt * TJ + t;
  bool ok = j < J_;
  float v[K_];
#pragma unroll
  for (int k = 0; k < K_; k++) {
    float2 p = ok ? V2[(size_t)k * J_ + j] : make_float2(0.f, 0.f);
    v[k] = (n == 0) ? p.x : p.y;
  }
  int i0 = s * ISEG, i1 = min(i0 + ISEG, I_);
  const float* yb = YdR + (size_t)n * I_ * J_;
  float nV[K_] = {}, dV[K_] = {};
  for (int i = i0; i < i1; i++) {
    float Tn[K_];
#pragma unroll
    for (int k = 0; k < K_; k++) Tn[k] = T[i * 2 * K_ + k * 2 + n];
    float ydr = ok ? yb[(size_t)i * J_ + j] : 0.f;
    float R = 0.f;
#pragma unroll
    for (int k = 0; k < K_; k++) R += Tn[k] * v[k];
    float rd2 = 1.f / (R + EPS);
#pragma unroll
    for (int k = 0; k < K_; k++) {
      nV[k] += Tn[k] * ydr;
      dV[k] += Tn[k] * rd2;
    }
  }
  if (ok) {
    size_t b0 = ((size_t)((s * 2 + n) * 2 + 0) * K_) * J_;
    size_t b1 = ((size_t)((s * 2 + n) * 2 + 1) * K_) * J_;
#pragma unroll
    for (int k = 0; k < K_; k++) partial[b0 + (size_t)k * J_ + j] = nV[k];
#pragma unroll
    for (int k = 0; k < K_; k++) partial[b1 + (size_t)k * J_ + j] = dV[k];
  }
}

// ---------------- finalize V ----------------
__global__ void k_finV(const float* __restrict__ partial, float2* V2) {
  int idx = blockIdx.x * 256 + threadIdx.x;
  if (idx >= K_ * J_) return;
  int k = idx / J_, j = idx - k * J_;
  float res[2];
#pragma unroll
  for (int n = 0; n < 2; n++) {
    float num = 0.f, den = 0.f;
    for (int s = 0; s < NSEG; s++) {
      num += partial[((size_t)((s * 2 + n) * 2 + 0) * K_ + k) * J_ + j];
      den += partial[((size_t)((s * 2 + n) * 2 + 1) * K_ + k) * J_ + j];
    }
    res[n] = sqrtf(num / (den + EPS));
  }
  float2 vo = V2[idx];
  V2[idx] = make_float2(vo.x * res[0], vo.y * res[1]);
}

// ---------------- pass C: covariances D0,D1 + both IP updates ----------------
__global__ __launch_bounds__(256) void k_passC(const float2* __restrict__ Xt,
                                               const float* __restrict__ T,
                                               const float2* __restrict__ V2,
                                               float2* W2) {
  int i = blockIdx.x, t = threadIdx.x;
  float T0[K_], T1[K_];
#pragma unroll
  for (int k = 0; k < K_; k++) {
    T0[k] = T[i * 2 * K_ + k * 2 + 0];
    T1[k] = T[i * 2 * K_ + k * 2 + 1];
  }
  const float2* x0r = Xt + (size_t)i * J_;
  const float2* x1r = Xt + ((size_t)I_ + i) * J_;
  float a[8] = {};  // d0_00 d0_11 d0_re d0_im d1_00 d1_11 d1_re d1_im
  for (int j = t; j < J_; j += 256) {
    float2 x0 = x0r[j], x1 = x1r[j];
    float R0 = 0.f, R1 = 0.f;
#pragma unroll
    for (int k = 0; k < K_; k++) {
      float2 p = V2[(size_t)k * J_ + j];
      R0 += T0[k] * p.x;
      R1 += T1[k] * p.y;
    }
    float inv0 = 1.f / (R0 + EPS), inv1 = 1.f / (R1 + EPS);
    float n00 = x0.x * x0.x + x0.y * x0.y;
    float n11 = x1.x * x1.x + x1.y * x1.y;
    float cre = x0.x * x1.x + x0.y * x1.y;  // Re(x0*conj(x1))
    float cim = x0.y * x1.x - x0.x * x1.y;  // Im(x0*conj(x1))
    a[0] += n00 * inv0; a[1] += n11 * inv0; a[2] += cre * inv0; a[3] += cim * inv0;
    a[4] += n00 * inv1; a[5] += n11 * inv1; a[6] += cre * inv1; a[7] += cim * inv1;
  }
  __shared__ float red[4][8];
  __shared__ float out[8];
  int wave = t >> 6, lane = t & 63;
#pragma unroll
  for (int q = 0; q < 8; q++) {
    float v = waveRed(a[q]);
    if (lane == 0) red[wave][q] = v;
  }
  __syncthreads();
  if (t < 8) out[t] = red[0][t] + red[1][t] + red[2][t] + red[3][t];
  __syncthreads();
  if (t == 0) {
    const double Jinv = 1.0 / (double)J_;
    double D[2][4];
#pragma unroll
    for (int s = 0; s < 2; s++) {
      D[s][0] = (double)out[s * 4 + 0] * Jinv + (double)EPS;
      D[s][1] = (double)out[s * 4 + 1] * Jinv + (double)EPS;
      D[s][2] = (double)out[s * 4 + 2] * Jinv;
      D[s][3] = (double)out[s * 4 + 3] * Jinv;
    }
    double W[2][2][2];
#pragma unroll
    for (int r = 0; r < 2; r++)
#pragma unroll
      for (int c = 0; c < 2; c++) {
        float2 w = W2[i * 4 + r * 2 + c];
        W[r][c][0] = w.x;
        W[r][c][1] = w.y;
      }
    for (int n = 0; n < 2; n++) {
      double d00 = D[n][0], d11 = D[n][1], dre = D[n][2], dim = D[n][3];
      double A[2][2][2];
#pragma unroll
      for (int r = 0; r < 2; r++) {
        A[r][0][0] = W[r][0][0] * d00 + (W[r][1][0] * dre + W[r][1][1] * dim);
        A[r][0][1] = W[r][0][1] * d00 + (W[r][1][1] * dre - W[r][1][0] * dim);
        A[r][1][0] = W[r][1][0] * d11 + (W[r][0][0] * dre - W[r][0][1] * dim);
        A[r][1][1] = W[r][1][1] * d11 + (W[r][0][1] * dre + W[r][0][0] * dim);
      }
      double detre = A[0][0][0] * A[1][1][0] - A[0][0][1] * A[1][1][1]
                   - (A[0][1][0] * A[1][0][0] - A[0][1][1] * A[1][0][1]);
      double detim = A[0][0][0] * A[1][1][1] + A[0][0][1] * A[1][1][0]
                   - (A[0][1][0] * A[1][0][1] + A[0][1][1] * A[1][0][0]);
      double b0re, b0im, b1re, b1im;
      if (n == 0) { b0re = A[1][1][0]; b0im = A[1][1][1]; b1re = -A[1][0][0]; b1im = -A[1][0][1]; }
      else        { b0re = -A[0][1][0]; b0im = -A[0][1][1]; b1re = A[0][0][0]; b1im = A[0][0][1]; }
      double dmag = detre * detre + detim * detim;
      double t0re = (b0re * detre + b0im * detim) / dmag, t0im = (b0im * detre - b0re * detim) / dmag;
      double t1re = (b1re * detre + b1im * detim) / dmag, t1im = (b1im * detre - b1re * detim) / dmag;
      double pre = t0re * t1re + t0im * t1im, pim = t0re * t1im - t0im * t1re;
      double quad = d00 * (t0re * t0re + t0im * t0im) + d11 * (t1re * t1re + t1im * t1im)
                  + 2.0 * (dre * pre - dim * pim);
      double denom = sqrt(quad + (double)EPS);
      double w0re = t0re / denom, w0im = -t0im / denom;
      double w1re = t1re / denom, w1im = -t1im / denom;
      W[n][0][0] = w0re; W[n][0][1] = w0im; W[n][1][0] = w1re; W[n][1][1] = w1im;
      W2[i * 4 + n * 2 + 0] = make_float2((float)w0re, (float)w0im);
      W2[i * 4 + n * 2 + 1] = make_float2((float)w1re, (float)w1im);
    }
  }
}

// ---------------- final output: Y = W X, transposed to (N,J,I) ----------------
__global__ __launch_bounds__(256) void k_output(const float2* __restrict__ Xt,
                                                const float2* __restrict__ W2,
                                                float2* __restrict__ out) {
  __shared__ float2 tile[2][32][33];
  int i0 = blockIdx.x * 32, j0 = blockIdx.y * 32;
  int tx = threadIdx.x & 31, ty = threadIdx.x >> 5;
  for (int r = ty; r < 32; r += 8) {
    int i = i0 + r, j = j0 + tx;
    if (i < I_ && j < J_) {
      float2 w00 = W2[i * 4 + 0], w01 = W2[i * 4 + 1], w10 = W2[i * 4 + 2], w11 = W2[i * 4 + 3];
      float2 x0 = Xt[(size_t)i * J_ + j], x1 = Xt[((size_t)I_ + i) * J_ + j];
      tile[0][r][tx] = make_float2(w00.x * x0.x - w00.y * x0.y + w01.x * x1.x - w01.y * x1.y,
                                   w00.x * x0.y + w00.y * x0.x + w01.x * x1.y + w01.y * x1.x);
      tile[1][r][tx] = make_float2(w10.x * x0.x - w10.y * x0.y + w11.x * x1.x - w11.y * x1.y,
                                   w10.x * x0.y + w10.y * x0.x + w11.x * x1.y + w11.y * x1.x);
    }
  }
  __syncthreads();
  for (int r = ty; r < 32; r += 8) {
    int j = j0 + r, i = i0 + tx;
    if (i < I_ && j < J_) {
      out[((size_t)0 * J_ + j) * I_ + i] = tile[0][tx][r];
      out[((size_t)1 * J_ + j) * I_ + i] = tile[1][tx][r];
    }
  }
}

extern "C" void kernel_launch(void* const* d_in, const int* in_sizes, int n_in,
                              void* d_out, int out_size, void* d_ws, size_t ws_size,
                              hipStream_t stream) {
  const float* X = (const float*)d_in[0];
  const float* Tin = (const float*)d_in[1];
  const float* Vin = (const float*)d_in[2];

  char* ws = (char*)d_ws;
  size_t off = 0;
  auto alloc = [&](size_t bytes) {
    void* p = ws + off;
    off = (off + bytes + 255) & ~(size_t)255;
    return p;
  };
  float2* Xt = (float2*)alloc((size_t)M_ * I_ * J_ * sizeof(float2));
  float* YdR = (float*)alloc((size_t)2 * I_ * J_ * sizeof(float));
  float2* V2 = (float2*)alloc((size_t)K_ * J_ * sizeof(float2));
  float* T = (float*)alloc((size_t)I_ * K_ * 2 * sizeof(float));
  float2* W2 = (float2*)alloc((size_t)I_ * 4 * sizeof(float2));
  float* partial = (float*)alloc((size_t)NSEG * 2 * 2 * K_ * J_ * sizeof(float));
  (void)ws_size; (void)in_sizes; (void)n_in; (void)out_size;

  k_init<<<(I_ * K_ * 2 + 255) / 256, 256, 0, stream>>>(Tin, Vin, T, V2, W2);
  dim3 tg((I_ + 31) / 32, (J_ + 31) / 32, 2);
  k_transpose<<<tg, 256, 0, stream>>>((const float2*)X, Xt);
  for (int it = 0; it < NITER; it++) {
    k_passA<<<I_, 256, 0, stream>>>(Xt, W2, T, V2, YdR);
    k_passB<<<dim3(NJT, NSEG, 2), 256, 0, stream>>>(T, V2, YdR, partial);
    k_finV<<<(K_ * J_ + 255) / 256, 256, 0, stream>>>(partial, V2);
    k_passC<<<I_, 256, 0, stream>>>(Xt, T, V2, W2);
  }
  dim3 og((I_ + 31) / 32, (J_ + 31) / 32);
  k_output<<<og, 256, 0, stream>>>(Xt, W2, (float2*)d_out);
}